// Round 12
// baseline (576.496 us; speedup 1.0000x reference)
//
#include <hip/hip_runtime.h>
#include <math.h>

typedef __bf16 bf16_t;
typedef __bf16 bf16x2 __attribute__((ext_vector_type(2)));
typedef __bf16 bf16x8 __attribute__((ext_vector_type(8)));
typedef float f32x4 __attribute__((ext_vector_type(4)));

#define BATCH   32
#define SEQ     1024
#define DMODEL  1024
#define NHEADS  16
#define DIMH    64
#define TEXTLEN 77
#define IMGLEN  256
#define CTXLEN  333
#define MAXREL  1024

#define MFMA16(a,b,c) __builtin_amdgcn_mfma_f32_16x16x32_bf16(a, b, c, 0, 0, 0)
#define SCALE_LOG2E 0.1803368809f   // 0.125 * log2(e)

__device__ __forceinline__ unsigned pk2(float a, float b) {
  union { bf16x2 v; unsigned u; } t;
  t.v[0] = (bf16_t)a; t.v[1] = (bf16_t)b;
  return t.u;
}

// ---------------------------------------------------------------- converts
__global__ __launch_bounds__(256) void k_cvt_x(const float* __restrict__ in,
                                               bf16_t* __restrict__ out) {
  size_t idx = ((size_t)blockIdx.x * blockDim.x + threadIdx.x) * 8;
  float4 a = *(const float4*)(in + idx);
  float4 b = *(const float4*)(in + idx + 4);
  bf16x8 o;
  o[0] = (bf16_t)a.x; o[1] = (bf16_t)a.y; o[2] = (bf16_t)a.z; o[3] = (bf16_t)a.w;
  o[4] = (bf16_t)b.x; o[5] = (bf16_t)b.y; o[6] = (bf16_t)b.z; o[7] = (bf16_t)b.w;
  *(bf16x8*)(out + idx) = o;
}

// text rows -> CtxT[b*80+t] (rows 77..79 zeroed), image rows -> CtxI[b*256+u]
__global__ __launch_bounds__(128) void k_cvt_ctx(const float* __restrict__ ctx,
                                                 bf16_t* __restrict__ ctxT,
                                                 bf16_t* __restrict__ ctxI) {
  int row = blockIdx.x;
  int b = row / CTXLEN, t = row - b * CTXLEN;
  const float* src = ctx + (size_t)row * DMODEL + threadIdx.x * 8;
  bf16_t* dst = (t < TEXTLEN)
      ? ctxT + ((size_t)(b * 80 + t)) * DMODEL + threadIdx.x * 8
      : ctxI + ((size_t)(b * IMGLEN + (t - TEXTLEN))) * DMODEL + threadIdx.x * 8;
  float4 a = *(const float4*)(src);
  float4 c = *(const float4*)(src + 4);
  bf16x8 o;
  o[0] = (bf16_t)a.x; o[1] = (bf16_t)a.y; o[2] = (bf16_t)a.z; o[3] = (bf16_t)a.w;
  o[4] = (bf16_t)c.x; o[5] = (bf16_t)c.y; o[6] = (bf16_t)c.z; o[7] = (bf16_t)c.w;
  *(bf16x8*)dst = o;
  if (t == 0) {
    bf16x8 z = {};
    #pragma unroll
    for (int rr = 77; rr < 80; ++rr)
      *(bf16x8*)(ctxT + ((size_t)(b * 80 + rr)) * DMODEL + threadIdx.x * 8) = z;
  }
}

// all 6 weight transposes in one launch (blockIdx.z selects weight)
__global__ void k_transpose_w6(const float* __restrict__ W0, const float* __restrict__ W1,
                               const float* __restrict__ W2, const float* __restrict__ W3,
                               const float* __restrict__ W4, const float* __restrict__ W5,
                               bf16_t* __restrict__ WTs) {
  __shared__ float tile[32][33];
  const float* Ws[6] = {W0, W1, W2, W3, W4, W5};
  const float* W = Ws[blockIdx.z];
  bf16_t* WT = WTs + (size_t)blockIdx.z * 1048576;
  int x = threadIdx.x, y = threadIdx.y;
  int n0 = blockIdx.x * 32, k0 = blockIdx.y * 32;
  #pragma unroll
  for (int r = 0; r < 32; r += 8)
    tile[y + r][x] = W[(size_t)(k0 + y + r) * DMODEL + n0 + x];
  __syncthreads();
  #pragma unroll
  for (int r = 0; r < 32; r += 8)
    WT[(size_t)(n0 + y + r) * DMODEL + k0 + x] = (bf16_t)tile[x][y + r];
}

// Rkb[u][d] = bf16(rel_k[u+1][d]), u in [0,2048)
__global__ __launch_bounds__(256) void k_cvt_relk(const float* __restrict__ relk,
                                                  bf16_t* __restrict__ Rkb) {
  int idx = blockIdx.x * 256 + threadIdx.x;
  int u = idx >> 3, d0 = (idx & 7) * 8;
  const float* s = relk + (size_t)(u + 1) * DIMH + d0;
  float4 a = *(const float4*)s;
  float4 b = *(const float4*)(s + 4);
  bf16x8 o;
  o[0] = (bf16_t)a.x; o[1] = (bf16_t)a.y; o[2] = (bf16_t)a.z; o[3] = (bf16_t)a.w;
  o[4] = (bf16_t)b.x; o[5] = (bf16_t)b.y; o[6] = (bf16_t)b.z; o[7] = (bf16_t)b.w;
  *(bf16x8*)(Rkb + (size_t)u * DIMH + d0) = o;
}

// RvT[d][u] = bf16(rel_v[u+1][d])  [64][2048]
__global__ __launch_bounds__(256) void k_cvt_relvT(const float* __restrict__ relv,
                                                   bf16_t* __restrict__ RvT) {
  int idx = blockIdx.x * 256 + threadIdx.x;
  int d = idx >> 8, u0 = (idx & 255) * 8;
  bf16x8 o;
  #pragma unroll
  for (int e = 0; e < 8; ++e)
    o[e] = (bf16_t)relv[(size_t)(u0 + e + 1) * DIMH + d];
  *(bf16x8*)(RvT + (size_t)d * 2048 + u0) = o;
}

// ---------------------------------------------------------------- GEMM
typedef __attribute__((address_space(1))) void gvoid;
typedef __attribute__((address_space(3))) void svoid;

__device__ __forceinline__ void async_ld16(const void* g, void* l) {
  __builtin_amdgcn_global_load_lds((gvoid*)g, (svoid*)l, 16, 0, 0);
}

// C = A(MxK bf16) * BT(NxK bf16)^T.  BM=256 x BN=128, 512 thr / 8 waves.
// Double-buffered, counted vmcnt(3), raw barriers, (row&3)-XOR chunk swizzle.
template<int STORE, bool AHM>
__global__ __launch_bounds__(512) void k_gemm(
    const bf16_t* __restrict__ A16, const bf16_t* __restrict__ BT,
    void* __restrict__ Cout, void* __restrict__ Cout2,
    const float* __restrict__ bias, int M, int N, int K)
{
  __shared__ __align__(16) bf16_t lds_a[2][256 * 32];   // 16 KB per buffer
  __shared__ __align__(16) bf16_t lds_b[2][128 * 32];   // 8 KB per buffer
  const int tid = threadIdx.x;
  const int wid = tid >> 6, lane = tid & 63;
  const int nx = gridDim.x, ny = gridDim.y;
  const int lin = blockIdx.y * nx + blockIdx.x;
  const int nwg = nx * ny;
  const int swz = (lin & 7) * (nwg >> 3) + (lin >> 3);
  const int bcol = (swz % ny) * 128;
  const int brow = (swz / ny) * 256;
  const int wr = (wid >> 1) * 64, wc = (wid & 1) * 64;
  const int lhi = lane >> 4, llo = lane & 15;

  auto stage = [&](int kk, int buf) __attribute__((always_inline)) {
    #pragma unroll
    for (int ch = 0; ch < 2; ++ch) {
      int cid = ch * 512 + tid;
      int row = cid >> 2, ccol = cid & 3;
      int gcol = (ccol ^ (row & 3)) << 3;
      const bf16_t* src;
      if constexpr (AHM) {
        int grow = brow + row;
        src = A16 + (((size_t)((grow >> 10) * 16 + (kk >> 6)) * 1024 + (grow & 1023)) << 6)
              + (kk & 32) + gcol;
      } else {
        src = A16 + (size_t)(brow + row) * K + kk + gcol;
      }
      async_ld16(src, (char*)lds_a[buf] + cid * 16);
    }
    {
      int row = tid >> 2, ccol = tid & 3;
      int gcol = (ccol ^ (row & 3)) << 3;
      async_ld16(BT + (size_t)(bcol + row) * K + kk + gcol,
                 (char*)lds_b[buf] + tid * 16);
    }
  };

  f32x4 acc[4][4];
  #pragma unroll
  for (int m = 0; m < 4; ++m)
    #pragma unroll
    for (int n = 0; n < 4; ++n)
      acc[m][n] = (f32x4){0.f, 0.f, 0.f, 0.f};

  stage(0, 0);
  int cur = 0;
  for (int kk = 0; kk < K; kk += 32) {
    if (kk + 32 < K) {
      stage(kk + 32, cur ^ 1);
      __builtin_amdgcn_sched_barrier(0);
      asm volatile("s_waitcnt vmcnt(3)" ::: "memory");
      __builtin_amdgcn_sched_barrier(0);
    } else {
      asm volatile("s_waitcnt vmcnt(0)" ::: "memory");
    }
    __builtin_amdgcn_s_barrier();

    bf16x8 af[4], bfv[4];
    #pragma unroll
    for (int m = 0; m < 4; ++m) {
      int row = wr + m * 16 + llo;
      af[m] = *(const bf16x8*)((const char*)lds_a[cur] + row * 64
                               + ((lhi ^ (row & 3)) << 4));
    }
    #pragma unroll
    for (int n = 0; n < 4; ++n) {
      int row = wc + n * 16 + llo;
      bfv[n] = *(const bf16x8*)((const char*)lds_b[cur] + row * 64
                                + ((lhi ^ (row & 3)) << 4));
    }
    #pragma unroll
    for (int m = 0; m < 4; ++m)
      #pragma unroll
      for (int n = 0; n < 4; ++n)
        acc[m][n] = MFMA16(af[m], bfv[n], acc[m][n]);

    asm volatile("s_waitcnt lgkmcnt(0)" ::: "memory");
    __builtin_amdgcn_sched_barrier(0);
    __builtin_amdgcn_s_barrier();
    cur ^= 1;
  }

  #pragma unroll
  for (int m = 0; m < 4; ++m)
    #pragma unroll
    for (int n = 0; n < 4; ++n) {
      const int gc = bcol + wc + n * 16 + llo;
      #pragma unroll
      for (int r = 0; r < 4; ++r) {
        const int gr = brow + wr + m * 16 + lhi * 4 + r;
        float v = acc[m][n][r];
        if constexpr (STORE == 2) {
          ((float*)Cout)[(size_t)gr * N + gc] = v + bias[gc];
        } else if constexpr (STORE == 4) {
          int hh2 = gc >> 6;
          ((bf16_t*)Cout)[((((size_t)((gr >> 10) * 16 + hh2)) << 10) + (gr & 1023)) * 64
                          + (gc & 63)] = (bf16_t)v;
        } else if constexpr (STORE == 5) {
          int bb = (gr * 6554) >> 19;           // gr / 80
          int jj = gr - bb * 80;
          int hh2 = (gc & 1023) >> 6;
          bf16_t* dst = (gc < 1024) ? (bf16_t*)Cout : (bf16_t*)Cout2;
          dst[(((size_t)(bb * 16 + hh2) * 80 + jj) << 6) + (gc & 63)] = (bf16_t)v;
        } else {                                 // STORE == 6
          int bb = gr >> 8, uu = gr & 255;
          int hh2 = (gc & 1023) >> 6;
          bf16_t* dst = (gc < 1024) ? (bf16_t*)Cout : (bf16_t*)Cout2;
          dst[((((size_t)(bb * 16 + hh2)) << 8) + uu) * 64 + (gc & 63)] = (bf16_t)v;
        }
      }
    }
}

// ---------------------------------------------------------------- V transpose
// head-major V [bh][RPB][64] -> Vt[bh][64][OUTC], Vt[bh][d][u]
template<int RPB, int OUTC>
__global__ __launch_bounds__(256) void k_vtrans(const bf16_t* __restrict__ V,
                                                bf16_t* __restrict__ Vt) {
  __shared__ bf16_t tile[64][72];
  const int nt = (OUTC + 63) / 64;
  const int u0 = (blockIdx.x % nt) * 64;
  const int bh = blockIdx.x / nt;
  const int tid = threadIdx.x;
  const int ur = tid >> 2, cg = (tid & 3) * 16;
  {
    const bf16_t* src = V + (((size_t)bh * RPB + u0 + ur) << 6) + cg;
    *(bf16x8*)&tile[ur][cg] = *(const bf16x8*)src;
    *(bf16x8*)&tile[ur][cg + 8] = *(const bf16x8*)(src + 8);
  }
  __syncthreads();
  bf16x8 o0, o1;
  #pragma unroll
  for (int e = 0; e < 8; ++e) { o0[e] = tile[cg + e][ur]; o1[e] = tile[cg + 8 + e][ur]; }
  bf16_t* dst = Vt + (size_t)bh * 64 * OUTC + (size_t)ur * OUTC + u0 + cg;
  if (u0 + cg + 8 <= OUTC)  *(bf16x8*)dst = o0;
  if (u0 + cg + 16 <= OUTC) *(bf16x8*)(dst + 8) = o1;
}

// ---------------------------------------------------------------- TXT attention
// grid (2, 512), 256 threads = 4 waves; block = (half, bh), 512 queries (8 st/wave).
// Round-8 inner body; Q direct-to-reg; O-bounce ALIASED into p_l (both dead
// across phases; same-wave LDS ops are in program order) -> LDS 46.0KB -> 3 blocks/CU.
__global__ __launch_bounds__(256, 3) void k_txt(
    const bf16_t* __restrict__ Qh,    // [512][1024][64]
    const bf16_t* __restrict__ Kth,   // [512][80][64]  (rows 77..79 zero)
    const bf16_t* __restrict__ Vtt,   // [512][64][80]
    const bf16_t* __restrict__ Rkb,   // [2048][64]
    const bf16_t* __restrict__ RvT,   // [64][2048]
    bf16_t* __restrict__ Oh)          // [512][1024][64]
{
  __shared__ __align__(16) bf16_t kt_l[80 * 64];   // 10240B, rows 128B, xor-swizzled
  __shared__ __align__(16) bf16_t vt_l[64 * 80];   // 10240B, rows 160B, rot-swizzled
  __shared__ __align__(16) char p_l[4][6400];      // per-wave P (pitch 200) + O-bounce alias
  const int tid = threadIdx.x;
  const int w = tid >> 6, lane = tid & 63;
  const int c = lane & 15, g = lane >> 4;
  const int half = blockIdx.x;
  const int bh = blockIdx.y;

  // stage K_text (640 chunks of 16B)
  #pragma unroll
  for (int q = 0; q < 3; ++q) {
    int cid0 = q * 256 + w * 64;
    if (cid0 < 640) {
      int cid = cid0 + lane;
      int row = cid >> 3, cc = cid & 7;
      const bf16_t* src = Kth + (((size_t)bh * 80 + row) << 6) + ((cc ^ (row & 7)) << 3);
      async_ld16(src, (char*)kt_l + cid0 * 16);
    }
  }
  // stage V_text^T (640 chunks, 10 per 160B row, rotate-swizzled)
  #pragma unroll
  for (int q = 0; q < 3; ++q) {
    int cid0 = q * 256 + w * 64;
    if (cid0 < 640) {
      int cid = cid0 + lane;
      int row = cid / 10;
      int col = cid - row * 10;
      int colp = col - (row & 7); if (colp < 0) colp += 10;
      const bf16_t* src = Vtt + (size_t)bh * 5120 + row * 80 + colp * 8;
      async_ld16(src, (char*)vt_l + cid0 * 16);
    }
  }
  __syncthreads();

  bf16_t* p = (bf16_t*)p_l[w];
  char* obounce = p_l[w];                        // alias: O-bounce reuses P region
  const bf16_t* qbase = Qh + ((size_t)bh << 16);

  bf16x8 qa0, qa1;
  {
    const bf16_t* qp = qbase + ((size_t)(half * 512 + w * 128 + c) << 6) + g * 8;
    qa0 = *(const bf16x8*)qp;
    qa1 = *(const bf16x8*)(qp + 32);
  }

  for (int st = 0; st < 8; ++st) {
    const int iq = half * 512 + w * 128 + st * 16;
    const int ub = 1008 - iq;                    // rel table slice base (>=0)
    // prefetch next-st Q into regs (independent of this st's chain)
    bf16x8 qn0 = qa0, qn1 = qa1;
    if (st < 7) {
      const bf16_t* qp = qbase + ((size_t)(iq + 16 + c) << 6) + g * 8;
      qn0 = *(const bf16x8*)qp;
      qn1 = *(const bf16x8*)(qp + 32);
    }
    // T = Q @ Rk_slice^T : ta[n] covers u' = n*16 + c, u' in [0,96)
    f32x4 ta[6];
    #pragma unroll
    for (int n = 0; n < 6; ++n) ta[n] = (f32x4){0.f, 0.f, 0.f, 0.f};
    {
      const bf16_t* rp = Rkb + (size_t)(ub + c) * DIMH + g * 8;
      #pragma unroll
      for (int n = 0; n < 6; ++n) {
        bf16x8 b0 = *(const bf16x8*)(rp + n * 16 * DIMH);
        bf16x8 b1 = *(const bf16x8*)(rp + n * 16 * DIMH + 32);
        ta[n] = MFMA16(qa0, b0, ta[n]);
        ta[n] = MFMA16(qa1, b1, ta[n]);
      }
    }
    // S = Q @ K^T from LDS
    f32x4 s[5];
    #pragma unroll
    for (int n = 0; n < 5; ++n) s[n] = (f32x4){0.f, 0.f, 0.f, 0.f};
    {
      const int sw = (c & 7) << 4;
      #pragma unroll
      for (int n = 0; n < 5; ++n) {
        int rb = (n * 16 + c) * 128;
        bf16x8 k0 = *(const bf16x8*)((const char*)kt_l + rb + ((g << 4) ^ sw));
        bf16x8 k1 = *(const bf16x8*)((const char*)kt_l + rb + (((4 + g) << 4) ^ sw));
        s[n] = MFMA16(qa0, k0, s[n]);
        s[n] = MFMA16(qa1, k1, s[n]);
      }
    }
    // combine S + sheared T via shuffles; mask j >= 77
    float st4[5][4];
    #pragma unroll
    for (int r = 0; r < 4; ++r) {
      int il = 4 * g + r;
      int cz = c + 15 - il;                      // in [0,30]
      int srcl = (lane & 48) | (cz & 15);
      bool lo_pick = (cz >> 4) == 0;
      #pragma unroll
      for (int n = 0; n < 5; ++n) {
        float tlo = __shfl(ta[n][r], srcl);
        float thi = __shfl(ta[n + 1][r], srcl);
        float tv = lo_pick ? tlo : thi;
        int j = 16 * n + c;
        st4[n][r] = (j < TEXTLEN) ? (s[n][r] + tv) : -1e30f;
      }
    }
    // softmax over j (cols), per row r
    float rsum[4];
    #pragma unroll
    for (int r = 0; r < 4; ++r) {
      float m = st4[0][r];
      #pragma unroll
      for (int n = 1; n < 5; ++n) m = fmaxf(m, st4[n][r]);
      m = fmaxf(m, __shfl_xor(m, 1));
      m = fmaxf(m, __shfl_xor(m, 2));
      m = fmaxf(m, __shfl_xor(m, 4));
      m = fmaxf(m, __shfl_xor(m, 8));
      float ssum = 0.f;
      #pragma unroll
      for (int n = 0; n < 5; ++n) {
        float pv = exp2f((st4[n][r] - m) * SCALE_LOG2E);
        st4[n][r] = pv;
        ssum += pv;
      }
      ssum += __shfl_xor(ssum, 1);
      ssum += __shfl_xor(ssum, 2);
      ssum += __shfl_xor(ssum, 4);
      ssum += __shfl_xor(ssum, 8);
      rsum[r] = ssum;
    }
    // zero P, then write sheared + plain P (pitch 200)
    {
      bf16x8 z8 = {};
      #pragma unroll
      for (int z = 0; z < 7; ++z) {
        int off = z * 1024 + lane * 16;
        if (off < 6400)
          *(bf16x8*)((char*)p + off) = z8;
      }
      #pragma unroll
      for (int n = 0; n < 5; ++n)
        #pragma unroll
        for (int r = 0; r < 4; ++r) {
          int j = 16 * n + c;
          if (j < TEXTLEN) {
            int il = 4 * g + r;
            bf16_t pb = (bf16_t)st4[n][r];
            p[il * 200 + (j + 15 - il)] = pb;    // sheared, u' in [0,92)
            p[il * 200 + 96 + j] = pb;           // plain at [96,173)
          }
        }
    }
    // O^T = mfma(A=[RvT_slice | Vt], B=P'^T), K extent 192 (zeros beyond 176)
    f32x4 ot[4];
    #pragma unroll
    for (int dt = 0; dt < 4; ++dt) ot[dt] = (f32x4){0.f, 0.f, 0.f, 0.f};
    #pragma unroll
    for (int kt = 0; kt < 6; ++kt) {
      bf16x8 pf = *(const bf16x8*)(p + c * 200 + kt * 32 + g * 8);
      int klo = kt * 32 + g * 8;
      #pragma unroll
      for (int dt = 0; dt < 4; ++dt) {
        int d = dt * 16 + c;
        bf16x8 af;
        if (klo < 96) {
          af = *(const bf16x8*)(RvT + (size_t)d * 2048 + ub + klo);
        } else {
          int uv = klo - 96;
          int chunk = (uv >> 3) + (c & 7); if (chunk >= 10) chunk -= 10;
          af = *(const bf16x8*)((const char*)vt_l + d * 160 + chunk * 16);
        }
        ot[dt] = MFMA16(af, pf, ot[dt]);
      }
    }
    // per-query inv sums: query of column c -> (g_src = c>>2, r_src = c&3)
    int srcq = ((c >> 2) << 4) | c;
    float t0 = __shfl(rsum[0], srcq);
    float t1 = __shfl(rsum[1], srcq);
    float t2 = __shfl(rsum[2], srcq);
    float t3 = __shfl(rsum[3], srcq);
    float rs = (c & 2) ? ((c & 1) ? t3 : t2) : ((c & 1) ? t1 : t0);
    float inv = 1.f / rs;
    // frag write into O-bounce (aliases P region; P is dead after PV reads,
    // same-wave LDS ops retire in program order), then contiguous readout
    #pragma unroll
    for (int dt = 0; dt < 4; ++dt) {
      int chunk = dt * 2 + (g >> 1);
      char* pa = obounce + c * 128 + ((chunk ^ (c & 7)) << 4) + (g & 1) * 8;
      uint2 nv;
      nv.x = pk2(ot[dt][0] * inv, ot[dt][1] * inv);
      nv.y = pk2(ot[dt][2] * inv, ot[dt][3] * inv);
      *(uint2*)pa = nv;
    }
    char* ob = (char*)(Oh + (((size_t)bh * 1024 + iq) << 6));
    #pragma unroll
    for (int k2 = 0; k2 < 2; ++k2) {
      int k = k2 * 64 + lane, rr = k >> 3, cc = k & 7;
      uint4 v = *(uint4*)(obounce + rr * 128 + ((cc ^ (rr & 7)) << 4));
      *(uint4*)(ob + rr * 128 + cc * 16) = v;
    }
    qa0 = qn0; qa1 = qn1;
  }
}

// ---------------------------------------------------------------- IMG attention
// grid (2, 512), 256 threads = 4 waves; block covers 512 queries (8 st/wave).
// RMW-adds into Oh (txt partial already there). Q direct-to-reg.
__global__ __launch_bounds__(256, 2) void k_img(
    const bf16_t* __restrict__ Qh,    // [512][1024][64]
    const bf16_t* __restrict__ Khi,   // [512][256][64]
    const bf16_t* __restrict__ Vipt,  // [512][64][256]
    const float* __restrict__ alpha,
    bf16_t* __restrict__ Oh)          // [512][1024][64]
{
  __shared__ __align__(16) bf16_t kst[256 * 64];   // 32KB, rows 128B, xor-swizzled
  __shared__ __align__(16) bf16_t vst[64 * 256];   // 32KB, rows 512B, xor-swizzled
  __shared__ __align__(16) char olds[4][2048];
  const int tid = threadIdx.x;
  const int w = tid >> 6, lane = tid & 63;
  const int c = lane & 15, g = lane >> 4;
  const int i0 = blockIdx.x * 512;
  const int bh = blockIdx.y;

  // stage K head-major (2048 chunks)
  #pragma unroll
  for (int q = 0; q < 8; ++q) {
    int cid = q * 256 + tid;
    int row = cid >> 3, cc = cid & 7;
    const bf16_t* src = Khi + (((size_t)bh * 256 + row) << 6) + ((cc ^ (row & 7)) << 3);
    async_ld16(src, (char*)kst + q * 4096 + w * 1024);
  }
  // stage V^T (2048 chunks)
  const char* vsrc0 = (const char*)(Vipt + (size_t)bh * 16384);
  #pragma unroll
  for (int q = 0; q < 8; ++q) {
    int L = (q * 256 + tid) * 16;
    int row = L >> 9;
    async_ld16(vsrc0 + (L ^ ((row & 7) << 4)), (char*)vst + q * 4096 + w * 1024);
  }
  // prologue O(0) prefetch
  {
    int iq = i0 + w * 128;
    #pragma unroll
    for (int k2 = 0; k2 < 2; ++k2) {
      int k = k2 * 64 + lane, rr = k >> 3, cc = k & 7;
      async_ld16(Oh + (((size_t)bh * 1024 + iq + rr) << 6) + ((cc ^ (rr & 7)) << 3),
                 olds[w] + k2 * 1024);
    }
  }
  __syncthreads();

  const float coef = tanhf(alpha[0]) + 1.0f;
  const bf16_t* qbase = Qh + ((size_t)bh << 16);

  bf16x8 qa0, qa1;
  {
    const bf16_t* qp = qbase + ((size_t)(i0 + w * 128 + c) << 6) + g * 8;
    qa0 = *(const bf16x8*)qp;
    qa1 = *(const bf16x8*)(qp + 32);
  }

  for (int st = 0; st < 8; ++st) {
    const int iq = i0 + w * 128 + st * 16;
    bf16x8 qn0 = qa0, qn1 = qa1;
    if (st < 7) {
      const bf16_t* qp = qbase + ((size_t)(iq + 16 + c) << 6) + g * 8;
      qn0 = *(const bf16x8*)qp;
      qn1 = *(const bf16x8*)(qp + 32);
    }
    f32x4 acc[4];
    #pragma unroll
    for (int dt = 0; dt < 4; ++dt) acc[dt] = (f32x4){0.f, 0.f, 0.f, 0.f};
    float m_run = -1e30f, l_run = 0.f;

    #pragma unroll
    for (int jt = 0; jt < 2; ++jt) {
      // S^T tile: mfma(K, Q) -> lane holds S^T[j=16n+4g+r][i=c]
      f32x4 s2[8];
      #pragma unroll
      for (int n = 0; n < 8; ++n) s2[n] = (f32x4){0.f, 0.f, 0.f, 0.f};
      const int sw = (c & 7) << 4;
      #pragma unroll
      for (int n = 0; n < 8; ++n) {
        int rb = (jt * 128 + n * 16 + c) * 128;
        bf16x8 k0 = *(const bf16x8*)((const char*)kst + rb + ((g << 4) ^ sw));
        bf16x8 k1 = *(const bf16x8*)((const char*)kst + rb + (((4 + g) << 4) ^ sw));
        s2[n] = MFMA16(k0, qa0, s2[n]);
        s2[n] = MFMA16(k1, qa1, s2[n]);
      }
      // online softmax over columns (i = c): stats lane-local + xor over g
      float mx = -1e30f;
      #pragma unroll
      for (int n = 0; n < 8; ++n)
        #pragma unroll
        for (int r = 0; r < 4; ++r) mx = fmaxf(mx, s2[n][r]);
      mx = fmaxf(mx, __shfl_xor(mx, 16));
      mx = fmaxf(mx, __shfl_xor(mx, 32));
      float m_new = fmaxf(m_run, mx);
      float fscale = exp2f((m_run - m_new) * SCALE_LOG2E);
      float tsum = 0.f;
      #pragma unroll
      for (int n = 0; n < 8; ++n)
        #pragma unroll
        for (int r = 0; r < 4; ++r) {
          float pv = exp2f((s2[n][r] - m_new) * SCALE_LOG2E);
          s2[n][r] = pv; tsum += pv;
        }
      tsum += __shfl_xor(tsum, 16);
      tsum += __shfl_xor(tsum, 32);
      l_run = l_run * fscale + tsum;
      m_run = m_new;
      #pragma unroll
      for (int dt = 0; dt < 4; ++dt) acc[dt] *= fscale;
      // PV: in-register P^T redistribution -> B-frag; A = V^T from LDS
      const int srcA = c | ((g & 1) << 5);
      const int srcB = srcA + 16;
      const bool hi_n = ((g >> 1) & 1) != 0;
      #pragma unroll
      for (int kt = 0; kt < 4; ++kt) {
        unsigned lo0 = pk2(s2[2 * kt][0], s2[2 * kt][1]);
        unsigned hi0 = pk2(s2[2 * kt][2], s2[2 * kt][3]);
        unsigned lo1 = pk2(s2[2 * kt + 1][0], s2[2 * kt + 1][1]);
        unsigned hi1 = pk2(s2[2 * kt + 1][2], s2[2 * kt + 1][3]);
        unsigned a0 = __shfl(lo0, srcA), a1 = __shfl(lo1, srcA);
        unsigned b0 = __shfl(hi0, srcA), b1 = __shfl(hi1, srcA);
        unsigned c0 = __shfl(lo0, srcB), c1 = __shfl(lo1, srcB);
        unsigned d0 = __shfl(hi0, srcB), d1 = __shfl(hi1, srcB);
        union { unsigned u[4]; bf16x8 v; } pf;
        pf.u[0] = hi_n ? a1 : a0;
        pf.u[1] = hi_n ? b1 : b0;
        pf.u[2] = hi_n ? c1 : c0;
        pf.u[3] = hi_n ? d1 : d0;
        #pragma unroll
        for (int dt = 0; dt < 4; ++dt) {
          int d = dt * 16 + c;
          int a = (d * 512 + jt * 256 + kt * 64 + g * 16) ^ ((c & 7) << 4);
          bf16x8 vf = *(const bf16x8*)((const char*)vst + a);
          acc[dt] = MFMA16(vf, pf.v, acc[dt]);
        }
      }
    }
    float inv = coef / l_run;
    asm volatile("s_waitcnt vmcnt(0)" ::: "memory");   // O(st) staged (+qn arrived)
    #pragma unroll
    for (int dt = 0; dt < 4; ++dt) {
      int chunk = dt * 2 + (g >> 1);
      char* pa = olds[w] + c * 128 + ((chunk ^ (c & 7)) << 4) + (g & 1) * 8;
      union { uint2 u2; bf16_t e[4]; } ov; ov.u2 = *(uint2*)pa;
      uint2 nv;
      nv.x = pk2((float)ov.e[0] + acc[dt][0] * inv, (float)ov.e[1] + acc[dt][1] * inv);
      nv.y = pk2((float)ov.e[2] + acc[dt][2] * inv, (float)ov.e[3] + acc[dt][3] * inv);
      *(uint2*)pa = nv;
    }
    char* ob = (char*)(Oh + (((size_t)bh * 1024 + iq) << 6));
    #pragma unroll
    for (int k2 = 0; k2 < 2; ++k2) {
      int k = k2 * 64 + lane, rr = k >> 3, cc = k & 7;
      uint4 v = *(uint4*)(olds[w] + rr * 128 + ((cc ^ (rr & 7)) << 4));
      *(uint4*)(ob + rr * 128 + cc * 16) = v;
    }
    asm volatile("s_waitcnt lgkmcnt(0)" ::: "memory"); // readout ds_reads retired
    if (st < 7) {
      int iqn = iq + 16;
      #pragma unroll
      for (int k2 = 0; k2 < 2; ++k2) {
        int k = k2 * 64 + lane, rr = k >> 3, cc = k & 7;
        async_ld16(Oh + (((size_t)bh * 1024 + iqn + rr) << 6) + ((cc ^ (rr & 7)) << 3),
                   olds[w] + k2 * 1024);
      }
    }
    qa0 = qn0; qa1 = qn1;
  }
}

// ---------------------------------------------------------------- launch
extern "C" void kernel_launch(void* const* d_in, const int* in_sizes, int n_in,
                              void* d_out, int out_size, void* d_ws, size_t ws_size,
                              hipStream_t stream)
{
  const float* x     = (const float*)d_in[0];
  const float* ctx   = (const float*)d_in[1];
  const float* W_q   = (const float*)d_in[2];
  const float* W_k   = (const float*)d_in[3];
  const float* W_v   = (const float*)d_in[4];
  const float* W_kip = (const float*)d_in[5];
  const float* W_vip = (const float*)d_in[6];
  const float* rel_k = (const float*)d_in[7];
  const float* rel_v = (const float*)d_in[8];
  const float* W_out = (const float*)d_in[9];
  const float* b_out = (const float*)d_in[10];
  const float* alpha = (const float*)d_in[11];

  char* ws = (char*)d_ws;
  bf16_t* Oh   = (bf16_t*)(ws + 0);            // [512][1024][64] (64MB)
  bf16_t* Qh   = (bf16_t*)(ws + 67108864);     // [512][1024][64] (64MB)
  bf16_t* CtxT = (bf16_t*)(ws + 134217728);    // [2560][1024] (5MB, 80 rows/b, 3 zero)
  bf16_t* CtxI = (bf16_t*)(ws + 139460608);    // [8192][1024] (16MB)
  bf16_t* WTs  = (bf16_t*)(ws + 156237824);    // 6 x 1024x1024 (12MB)
  bf16_t* WqT   = WTs + 0 * 1048576;
  bf16_t* WkT   = WTs + 1 * 1048576;   // WkT/WvT contiguous => N=2048 GEMM
  bf16_t* WkipT = WTs + 3 * 1048576;
  bf16_t* WoutT = WTs + 5 * 1048576;

  char* dob = (char*)d_out;
  bf16_t* Khi   = (bf16_t*)(dob + 0);           // [512][256][64] (16MB)
  bf16_t* Vhi   = (bf16_t*)(dob + 16777216);    // [512][256][64] (16MB)
  bf16_t* Vipt  = (bf16_t*)(dob + 33554432);    // [512][64][256] (16MB)
  bf16_t* Kth   = (bf16_t*)(dob + 50331648);    // [512][80][64] (5MB)
  bf16_t* Vth   = (bf16_t*)(dob + 55574528);    // [512][80][64] (5MB)
  bf16_t* Vtt   = (bf16_t*)(dob + 60817408);    // [512][64][80] (5MB)
  bf16_t* Rkb   = (bf16_t*)(dob + 66060288);    // [2048][64] (256KB)
  bf16_t* RvT   = (bf16_t*)(dob + 66322432);    // [64][2048] (256KB)
  bf16_t* Xb    = (bf16_t*)(dob + 66584576);    // [32768][1024] bf16 (64MB), dead before out-GEMM

  // converts / transposes
  k_cvt_x<<<16384, 256, 0, stream>>>(x, Xb);
  k_cvt_ctx<<<BATCH * CTXLEN, 128, 0, stream>>>(ctx, CtxT, CtxI);
  k_transpose_w6<<<dim3(32, 32, 6), dim3(32, 8), 0, stream>>>(W_q, W_k, W_v, W_kip, W_vip, W_out, WTs);
  k_cvt_relk<<<64, 256, 0, stream>>>(rel_k, Rkb);
  k_cvt_relvT<<<64, 256, 0, stream>>>(rel_v, RvT);

  // projections (head-major outputs); BM=256 x BN=128, 512 threads
  k_gemm<4, false><<<dim3(128, 8),  512, 0, stream>>>(Xb,   WqT,   (void*)Qh,  nullptr,     nullptr, 32768, 1024, 1024);
  k_gemm<5, false><<<dim3(10, 16),  512, 0, stream>>>(CtxT, WkT,   (void*)Kth, (void*)Vth,  nullptr, 2560,  2048, 1024);
  k_gemm<6, false><<<dim3(32, 16),  512, 0, stream>>>(CtxI, WkipT, (void*)Khi, (void*)Vhi,  nullptr, 8192,  2048, 1024);

  // V transposes (head-major input)
  k_vtrans<80,  80 ><<<2 * 512, 256, 0, stream>>>(Vth, Vtt);
  k_vtrans<256, 256><<<4 * 512, 256, 0, stream>>>(Vhi, Vipt);

  // attention: txt writes Oh, img RMW-adds
  k_txt<<<dim3(2, 512), 256, 0, stream>>>(Qh, Kth, Vtt, Rkb, RvT, Oh);
  k_img<<<dim3(2, 512), 256, 0, stream>>>(Qh, Khi, Vipt, alpha, Oh);

  // output projection + bias (head-major A)
  k_gemm<2, true><<<dim3(128, 8), 512, 0, stream>>>(Oh, WoutT, d_out, nullptr, b_out, 32768, 1024, 1024);
}

// Round 13
// 516.757 us; speedup vs baseline: 1.1156x; 1.1156x over previous
//
#include <hip/hip_runtime.h>
#include <math.h>

typedef __bf16 bf16_t;
typedef __bf16 bf16x2 __attribute__((ext_vector_type(2)));
typedef __bf16 bf16x8 __attribute__((ext_vector_type(8)));
typedef float f32x4 __attribute__((ext_vector_type(4)));

#define BATCH   32
#define SEQ     1024
#define DMODEL  1024
#define NHEADS  16
#define DIMH    64
#define TEXTLEN 77
#define IMGLEN  256
#define CTXLEN  333
#define MAXREL  1024

#define MFMA16(a,b,c) __builtin_amdgcn_mfma_f32_16x16x32_bf16(a, b, c, 0, 0, 0)
#define SCALE_LOG2E 0.1803368809f   // 0.125 * log2(e)

__device__ __forceinline__ unsigned pk2(float a, float b) {
  union { bf16x2 v; unsigned u; } t;
  t.v[0] = (bf16_t)a; t.v[1] = (bf16_t)b;
  return t.u;
}

// ---------------------------------------------------------------- converts
__global__ __launch_bounds__(256) void k_cvt_x(const float* __restrict__ in,
                                               bf16_t* __restrict__ out) {
  size_t idx = ((size_t)blockIdx.x * blockDim.x + threadIdx.x) * 8;
  float4 a = *(const float4*)(in + idx);
  float4 b = *(const float4*)(in + idx + 4);
  bf16x8 o;
  o[0] = (bf16_t)a.x; o[1] = (bf16_t)a.y; o[2] = (bf16_t)a.z; o[3] = (bf16_t)a.w;
  o[4] = (bf16_t)b.x; o[5] = (bf16_t)b.y; o[6] = (bf16_t)b.z; o[7] = (bf16_t)b.w;
  *(bf16x8*)(out + idx) = o;
}

// text rows -> CtxT[b*80+t] (rows 77..79 zeroed), image rows -> CtxI[b*256+u]
__global__ __launch_bounds__(128) void k_cvt_ctx(const float* __restrict__ ctx,
                                                 bf16_t* __restrict__ ctxT,
                                                 bf16_t* __restrict__ ctxI) {
  int row = blockIdx.x;
  int b = row / CTXLEN, t = row - b * CTXLEN;
  const float* src = ctx + (size_t)row * DMODEL + threadIdx.x * 8;
  bf16_t* dst = (t < TEXTLEN)
      ? ctxT + ((size_t)(b * 80 + t)) * DMODEL + threadIdx.x * 8
      : ctxI + ((size_t)(b * IMGLEN + (t - TEXTLEN))) * DMODEL + threadIdx.x * 8;
  float4 a = *(const float4*)(src);
  float4 c = *(const float4*)(src + 4);
  bf16x8 o;
  o[0] = (bf16_t)a.x; o[1] = (bf16_t)a.y; o[2] = (bf16_t)a.z; o[3] = (bf16_t)a.w;
  o[4] = (bf16_t)c.x; o[5] = (bf16_t)c.y; o[6] = (bf16_t)c.z; o[7] = (bf16_t)c.w;
  *(bf16x8*)dst = o;
  if (t == 0) {
    bf16x8 z = {};
    #pragma unroll
    for (int rr = 77; rr < 80; ++rr)
      *(bf16x8*)(ctxT + ((size_t)(b * 80 + rr)) * DMODEL + threadIdx.x * 8) = z;
  }
}

// all 6 weight transposes in one launch (blockIdx.z selects weight)
__global__ void k_transpose_w6(const float* __restrict__ W0, const float* __restrict__ W1,
                               const float* __restrict__ W2, const float* __restrict__ W3,
                               const float* __restrict__ W4, const float* __restrict__ W5,
                               bf16_t* __restrict__ WTs) {
  __shared__ float tile[32][33];
  const float* Ws[6] = {W0, W1, W2, W3, W4, W5};
  const float* W = Ws[blockIdx.z];
  bf16_t* WT = WTs + (size_t)blockIdx.z * 1048576;
  int x = threadIdx.x, y = threadIdx.y;
  int n0 = blockIdx.x * 32, k0 = blockIdx.y * 32;
  #pragma unroll
  for (int r = 0; r < 32; r += 8)
    tile[y + r][x] = W[(size_t)(k0 + y + r) * DMODEL + n0 + x];
  __syncthreads();
  #pragma unroll
  for (int r = 0; r < 32; r += 8)
    WT[(size_t)(n0 + y + r) * DMODEL + k0 + x] = (bf16_t)tile[x][y + r];
}

// Rkb[u][d] = bf16(rel_k[u+1][d]), u in [0,2048)
__global__ __launch_bounds__(256) void k_cvt_relk(const float* __restrict__ relk,
                                                  bf16_t* __restrict__ Rkb) {
  int idx = blockIdx.x * 256 + threadIdx.x;
  int u = idx >> 3, d0 = (idx & 7) * 8;
  const float* s = relk + (size_t)(u + 1) * DIMH + d0;
  float4 a = *(const float4*)s;
  float4 b = *(const float4*)(s + 4);
  bf16x8 o;
  o[0] = (bf16_t)a.x; o[1] = (bf16_t)a.y; o[2] = (bf16_t)a.z; o[3] = (bf16_t)a.w;
  o[4] = (bf16_t)b.x; o[5] = (bf16_t)b.y; o[6] = (bf16_t)b.z; o[7] = (bf16_t)b.w;
  *(bf16x8*)(Rkb + (size_t)u * DIMH + d0) = o;
}

// RvT[d][u] = bf16(rel_v[u+1][d])  [64][2048]
__global__ __launch_bounds__(256) void k_cvt_relvT(const float* __restrict__ relv,
                                                   bf16_t* __restrict__ RvT) {
  int idx = blockIdx.x * 256 + threadIdx.x;
  int d = idx >> 8, u0 = (idx & 255) * 8;
  bf16x8 o;
  #pragma unroll
  for (int e = 0; e < 8; ++e)
    o[e] = (bf16_t)relv[(size_t)(u0 + e + 1) * DIMH + d];
  *(bf16x8*)(RvT + (size_t)d * 2048 + u0) = o;
}

// ---------------------------------------------------------------- GEMM
typedef __attribute__((address_space(1))) void gvoid;
typedef __attribute__((address_space(3))) void svoid;

__device__ __forceinline__ void async_ld16(const void* g, void* l) {
  __builtin_amdgcn_global_load_lds((gvoid*)g, (svoid*)l, 16, 0, 0);
}

// C = A(MxK bf16) * BT(NxK bf16)^T.  BM=256 x BN=128, 512 thr / 8 waves.
// Double-buffered, counted vmcnt(3), raw barriers, (row&3)-XOR chunk swizzle.
template<int STORE, bool AHM>
__global__ __launch_bounds__(512) void k_gemm(
    const bf16_t* __restrict__ A16, const bf16_t* __restrict__ BT,
    void* __restrict__ Cout, void* __restrict__ Cout2,
    const float* __restrict__ bias, int M, int N, int K)
{
  __shared__ __align__(16) bf16_t lds_a[2][256 * 32];   // 16 KB per buffer
  __shared__ __align__(16) bf16_t lds_b[2][128 * 32];   // 8 KB per buffer
  const int tid = threadIdx.x;
  const int wid = tid >> 6, lane = tid & 63;
  const int nx = gridDim.x, ny = gridDim.y;
  const int lin = blockIdx.y * nx + blockIdx.x;
  const int nwg = nx * ny;
  const int swz = (lin & 7) * (nwg >> 3) + (lin >> 3);
  const int bcol = (swz % ny) * 128;
  const int brow = (swz / ny) * 256;
  const int wr = (wid >> 1) * 64, wc = (wid & 1) * 64;
  const int lhi = lane >> 4, llo = lane & 15;

  auto stage = [&](int kk, int buf) __attribute__((always_inline)) {
    #pragma unroll
    for (int ch = 0; ch < 2; ++ch) {
      int cid = ch * 512 + tid;
      int row = cid >> 2, ccol = cid & 3;
      int gcol = (ccol ^ (row & 3)) << 3;
      const bf16_t* src;
      if constexpr (AHM) {
        int grow = brow + row;
        src = A16 + (((size_t)((grow >> 10) * 16 + (kk >> 6)) * 1024 + (grow & 1023)) << 6)
              + (kk & 32) + gcol;
      } else {
        src = A16 + (size_t)(brow + row) * K + kk + gcol;
      }
      async_ld16(src, (char*)lds_a[buf] + cid * 16);
    }
    {
      int row = tid >> 2, ccol = tid & 3;
      int gcol = (ccol ^ (row & 3)) << 3;
      async_ld16(BT + (size_t)(bcol + row) * K + kk + gcol,
                 (char*)lds_b[buf] + tid * 16);
    }
  };

  f32x4 acc[4][4];
  #pragma unroll
  for (int m = 0; m < 4; ++m)
    #pragma unroll
    for (int n = 0; n < 4; ++n)
      acc[m][n] = (f32x4){0.f, 0.f, 0.f, 0.f};

  stage(0, 0);
  int cur = 0;
  for (int kk = 0; kk < K; kk += 32) {
    if (kk + 32 < K) {
      stage(kk + 32, cur ^ 1);
      __builtin_amdgcn_sched_barrier(0);
      asm volatile("s_waitcnt vmcnt(3)" ::: "memory");
      __builtin_amdgcn_sched_barrier(0);
    } else {
      asm volatile("s_waitcnt vmcnt(0)" ::: "memory");
    }
    __builtin_amdgcn_s_barrier();

    bf16x8 af[4], bfv[4];
    #pragma unroll
    for (int m = 0; m < 4; ++m) {
      int row = wr + m * 16 + llo;
      af[m] = *(const bf16x8*)((const char*)lds_a[cur] + row * 64
                               + ((lhi ^ (row & 3)) << 4));
    }
    #pragma unroll
    for (int n = 0; n < 4; ++n) {
      int row = wc + n * 16 + llo;
      bfv[n] = *(const bf16x8*)((const char*)lds_b[cur] + row * 64
                                + ((lhi ^ (row & 3)) << 4));
    }
    #pragma unroll
    for (int m = 0; m < 4; ++m)
      #pragma unroll
      for (int n = 0; n < 4; ++n)
        acc[m][n] = MFMA16(af[m], bfv[n], acc[m][n]);

    asm volatile("s_waitcnt lgkmcnt(0)" ::: "memory");
    __builtin_amdgcn_sched_barrier(0);
    __builtin_amdgcn_s_barrier();
    cur ^= 1;
  }

  #pragma unroll
  for (int m = 0; m < 4; ++m)
    #pragma unroll
    for (int n = 0; n < 4; ++n) {
      const int gc = bcol + wc + n * 16 + llo;
      #pragma unroll
      for (int r = 0; r < 4; ++r) {
        const int gr = brow + wr + m * 16 + lhi * 4 + r;
        float v = acc[m][n][r];
        if constexpr (STORE == 2) {
          ((float*)Cout)[(size_t)gr * N + gc] = v + bias[gc];
        } else if constexpr (STORE == 4) {
          int hh2 = gc >> 6;
          ((bf16_t*)Cout)[((((size_t)((gr >> 10) * 16 + hh2)) << 10) + (gr & 1023)) * 64
                          + (gc & 63)] = (bf16_t)v;
        } else if constexpr (STORE == 5) {
          int bb = (gr * 6554) >> 19;           // gr / 80
          int jj = gr - bb * 80;
          int hh2 = (gc & 1023) >> 6;
          bf16_t* dst = (gc < 1024) ? (bf16_t*)Cout : (bf16_t*)Cout2;
          dst[(((size_t)(bb * 16 + hh2) * 80 + jj) << 6) + (gc & 63)] = (bf16_t)v;
        } else {                                 // STORE == 6
          int bb = gr >> 8, uu = gr & 255;
          int hh2 = (gc & 1023) >> 6;
          bf16_t* dst = (gc < 1024) ? (bf16_t*)Cout : (bf16_t*)Cout2;
          dst[((((size_t)(bb * 16 + hh2)) << 8) + uu) * 64 + (gc & 63)] = (bf16_t)v;
        }
      }
    }
}

// ---------------------------------------------------------------- V transpose
// head-major V [bh][RPB][64] -> Vt[bh][64][OUTC], Vt[bh][d][u]
template<int RPB, int OUTC>
__global__ __launch_bounds__(256) void k_vtrans(const bf16_t* __restrict__ V,
                                                bf16_t* __restrict__ Vt) {
  __shared__ bf16_t tile[64][72];
  const int nt = (OUTC + 63) / 64;
  const int u0 = (blockIdx.x % nt) * 64;
  const int bh = blockIdx.x / nt;
  const int tid = threadIdx.x;
  const int ur = tid >> 2, cg = (tid & 3) * 16;
  {
    const bf16_t* src = V + (((size_t)bh * RPB + u0 + ur) << 6) + cg;
    *(bf16x8*)&tile[ur][cg] = *(const bf16x8*)src;
    *(bf16x8*)&tile[ur][cg + 8] = *(const bf16x8*)(src + 8);
  }
  __syncthreads();
  bf16x8 o0, o1;
  #pragma unroll
  for (int e = 0; e < 8; ++e) { o0[e] = tile[cg + e][ur]; o1[e] = tile[cg + 8 + e][ur]; }
  bf16_t* dst = Vt + (size_t)bh * 64 * OUTC + (size_t)ur * OUTC + u0 + cg;
  if (u0 + cg + 8 <= OUTC)  *(bf16x8*)dst = o0;
  if (u0 + cg + 16 <= OUTC) *(bf16x8*)(dst + 8) = o1;
}

// ---------------------------------------------------------------- TXT attention
// ROUND-8 version: grid (512), 256 threads = 4 waves; block = bh, 16 st/wave.
// Q via qlds (global_load_lds), separate olds bounce. LDS 62.5KB, 2 blocks/CU.
__global__ __launch_bounds__(256, 2) void k_txt(
    const bf16_t* __restrict__ Qh,    // [512][1024][64]
    const bf16_t* __restrict__ Kth,   // [512][80][64]  (rows 77..79 zero)
    const bf16_t* __restrict__ Vtt,   // [512][64][80]
    const bf16_t* __restrict__ Rkb,   // [2048][64]
    const bf16_t* __restrict__ RvT,   // [64][2048]
    bf16_t* __restrict__ Oh)          // [512][1024][64]
{
  __shared__ __align__(16) bf16_t kt_l[80 * 64];   // 10240B, rows 128B, xor-swizzled
  __shared__ __align__(16) bf16_t vt_l[64 * 80];   // 10240B, rows 160B, rot-swizzled
  __shared__ __align__(16) char p_l[4][6400];      // per-wave P, pitch 200 elem
  __shared__ __align__(16) char qlds[4][2048];
  __shared__ __align__(16) char olds[4][2048];
  const int tid = threadIdx.x;
  const int w = tid >> 6, lane = tid & 63;
  const int c = lane & 15, g = lane >> 4;
  const int bh = blockIdx.x;

  // stage K_text (640 chunks of 16B)
  #pragma unroll
  for (int q = 0; q < 3; ++q) {
    int cid0 = q * 256 + w * 64;
    if (cid0 < 640) {
      int cid = cid0 + lane;
      int row = cid >> 3, cc = cid & 7;
      const bf16_t* src = Kth + (((size_t)bh * 80 + row) << 6) + ((cc ^ (row & 7)) << 3);
      async_ld16(src, (char*)kt_l + cid0 * 16);
    }
  }
  // stage V_text^T (640 chunks, 10 per 160B row, rotate-swizzled)
  #pragma unroll
  for (int q = 0; q < 3; ++q) {
    int cid0 = q * 256 + w * 64;
    if (cid0 < 640) {
      int cid = cid0 + lane;
      int row = cid / 10;
      int col = cid - row * 10;
      int colp = col - (row & 7); if (colp < 0) colp += 10;
      const bf16_t* src = Vtt + (size_t)bh * 5120 + row * 80 + colp * 8;
      async_ld16(src, (char*)vt_l + cid0 * 16);
    }
  }
  // prologue Q(0)
  {
    int iq = w * 256;
    #pragma unroll
    for (int k2 = 0; k2 < 2; ++k2) {
      int k = k2 * 64 + lane, rr = k >> 3, cc = k & 7;
      async_ld16(Qh + (((size_t)bh * 1024 + iq + rr) << 6) + ((cc ^ (rr & 7)) << 3),
                 qlds[w] + k2 * 1024);
    }
  }
  __syncthreads();

  bf16_t* p = (bf16_t*)p_l[w];

  for (int st = 0; st < 16; ++st) {
    const int iq = w * 256 + st * 16;
    const int ub = 1008 - iq;                    // rel table slice base (>=0)
    asm volatile("s_waitcnt vmcnt(0)" ::: "memory");
    bf16x8 qa0 = *(const bf16x8*)(qlds[w] + c * 128 + ((g ^ (c & 7)) << 4));
    bf16x8 qa1 = *(const bf16x8*)(qlds[w] + c * 128 + (((g + 4) ^ (c & 7)) << 4));
    asm volatile("s_waitcnt lgkmcnt(0)" ::: "memory");
    if (st < 15) {
      int iqn = iq + 16;
      #pragma unroll
      for (int k2 = 0; k2 < 2; ++k2) {
        int k = k2 * 64 + lane, rr = k >> 3, cc = k & 7;
        async_ld16(Qh + (((size_t)bh * 1024 + iqn + rr) << 6) + ((cc ^ (rr & 7)) << 3),
                   qlds[w] + k2 * 1024);
      }
    }
    // T = Q @ Rk_slice^T : ta[n] covers u' = n*16 + c, u' in [0,96)
    f32x4 ta[6];
    #pragma unroll
    for (int n = 0; n < 6; ++n) ta[n] = (f32x4){0.f, 0.f, 0.f, 0.f};
    {
      const bf16_t* rp = Rkb + (size_t)(ub + c) * DIMH + g * 8;
      #pragma unroll
      for (int n = 0; n < 6; ++n) {
        bf16x8 b0 = *(const bf16x8*)(rp + n * 16 * DIMH);
        bf16x8 b1 = *(const bf16x8*)(rp + n * 16 * DIMH + 32);
        ta[n] = MFMA16(qa0, b0, ta[n]);
        ta[n] = MFMA16(qa1, b1, ta[n]);
      }
    }
    // S = Q @ K^T from LDS
    f32x4 s[5];
    #pragma unroll
    for (int n = 0; n < 5; ++n) s[n] = (f32x4){0.f, 0.f, 0.f, 0.f};
    {
      const int sw = (c & 7) << 4;
      #pragma unroll
      for (int n = 0; n < 5; ++n) {
        int rb = (n * 16 + c) * 128;
        bf16x8 k0 = *(const bf16x8*)((const char*)kt_l + rb + ((g << 4) ^ sw));
        bf16x8 k1 = *(const bf16x8*)((const char*)kt_l + rb + (((4 + g) << 4) ^ sw));
        s[n] = MFMA16(qa0, k0, s[n]);
        s[n] = MFMA16(qa1, k1, s[n]);
      }
    }
    // combine S + sheared T via shuffles; mask j >= 77
    float st4[5][4];
    #pragma unroll
    for (int r = 0; r < 4; ++r) {
      int il = 4 * g + r;
      int cz = c + 15 - il;                      // in [0,30]
      int srcl = (lane & 48) | (cz & 15);
      bool lo_pick = (cz >> 4) == 0;
      #pragma unroll
      for (int n = 0; n < 5; ++n) {
        float tlo = __shfl(ta[n][r], srcl);
        float thi = __shfl(ta[n + 1][r], srcl);
        float tv = lo_pick ? tlo : thi;
        int j = 16 * n + c;
        st4[n][r] = (j < TEXTLEN) ? (s[n][r] + tv) : -1e30f;
      }
    }
    // softmax over j (cols), per row r
    float rsum[4];
    #pragma unroll
    for (int r = 0; r < 4; ++r) {
      float m = st4[0][r];
      #pragma unroll
      for (int n = 1; n < 5; ++n) m = fmaxf(m, st4[n][r]);
      m = fmaxf(m, __shfl_xor(m, 1));
      m = fmaxf(m, __shfl_xor(m, 2));
      m = fmaxf(m, __shfl_xor(m, 4));
      m = fmaxf(m, __shfl_xor(m, 8));
      float ssum = 0.f;
      #pragma unroll
      for (int n = 0; n < 5; ++n) {
        float pv = exp2f((st4[n][r] - m) * SCALE_LOG2E);
        st4[n][r] = pv;
        ssum += pv;
      }
      ssum += __shfl_xor(ssum, 1);
      ssum += __shfl_xor(ssum, 2);
      ssum += __shfl_xor(ssum, 4);
      ssum += __shfl_xor(ssum, 8);
      rsum[r] = ssum;
    }
    // zero P, then write sheared + plain P (pitch 200)
    {
      bf16x8 z8 = {};
      #pragma unroll
      for (int z = 0; z < 7; ++z) {
        int off = z * 1024 + lane * 16;
        if (off < 6400)
          *(bf16x8*)((char*)p + off) = z8;
      }
      #pragma unroll
      for (int n = 0; n < 5; ++n)
        #pragma unroll
        for (int r = 0; r < 4; ++r) {
          int j = 16 * n + c;
          if (j < TEXTLEN) {
            int il = 4 * g + r;
            bf16_t pb = (bf16_t)st4[n][r];
            p[il * 200 + (j + 15 - il)] = pb;    // sheared, u' in [0,92)
            p[il * 200 + 96 + j] = pb;           // plain at [96,173)
          }
        }
    }
    // O^T = mfma(A=[RvT_slice | Vt], B=P'^T), K extent 192 (zeros beyond 176)
    f32x4 ot[4];
    #pragma unroll
    for (int dt = 0; dt < 4; ++dt) ot[dt] = (f32x4){0.f, 0.f, 0.f, 0.f};
    #pragma unroll
    for (int kt = 0; kt < 6; ++kt) {
      bf16x8 pf = *(const bf16x8*)(p + c * 200 + kt * 32 + g * 8);
      int klo = kt * 32 + g * 8;
      #pragma unroll
      for (int dt = 0; dt < 4; ++dt) {
        int d = dt * 16 + c;
        bf16x8 af;
        if (klo < 96) {
          af = *(const bf16x8*)(RvT + (size_t)d * 2048 + ub + klo);
        } else {
          int uv = klo - 96;
          int chunk = (uv >> 3) + (c & 7); if (chunk >= 10) chunk -= 10;
          af = *(const bf16x8*)((const char*)vt_l + d * 160 + chunk * 16);
        }
        ot[dt] = MFMA16(af, pf, ot[dt]);
      }
    }
    // per-query inv sums: query of column c -> (g_src = c>>2, r_src = c&3)
    int srcq = ((c >> 2) << 4) | c;
    float t0 = __shfl(rsum[0], srcq);
    float t1 = __shfl(rsum[1], srcq);
    float t2 = __shfl(rsum[2], srcq);
    float t3 = __shfl(rsum[3], srcq);
    float rs = (c & 2) ? ((c & 1) ? t3 : t2) : ((c & 1) ? t1 : t0);
    float inv = 1.f / rs;
    // frag write into per-wave O bounce (swizzled), then contiguous readout
    #pragma unroll
    for (int dt = 0; dt < 4; ++dt) {
      int chunk = dt * 2 + (g >> 1);
      char* pa = olds[w] + c * 128 + ((chunk ^ (c & 7)) << 4) + (g & 1) * 8;
      uint2 nv;
      nv.x = pk2(ot[dt][0] * inv, ot[dt][1] * inv);
      nv.y = pk2(ot[dt][2] * inv, ot[dt][3] * inv);
      *(uint2*)pa = nv;
    }
    char* ob = (char*)(Oh + (((size_t)bh * 1024 + iq) << 6));
    #pragma unroll
    for (int k2 = 0; k2 < 2; ++k2) {
      int k = k2 * 64 + lane, rr = k >> 3, cc = k & 7;
      uint4 v = *(uint4*)(olds[w] + rr * 128 + ((cc ^ (rr & 7)) << 4));
      *(uint4*)(ob + rr * 128 + cc * 16) = v;
    }
  }
}

// ---------------------------------------------------------------- IMG attention
// ROUND-8 version: grid (2, 512), 256 threads = 4 waves; 8 st/wave.
// RMW-adds into Oh (txt partial already there). Q via qlds.
__global__ __launch_bounds__(256, 2) void k_img(
    const bf16_t* __restrict__ Qh,    // [512][1024][64]
    const bf16_t* __restrict__ Khi,   // [512][256][64]
    const bf16_t* __restrict__ Vipt,  // [512][64][256]
    const float* __restrict__ alpha,
    bf16_t* __restrict__ Oh)          // [512][1024][64]
{
  __shared__ __align__(16) bf16_t kst[256 * 64];   // 32KB, rows 128B, xor-swizzled
  __shared__ __align__(16) bf16_t vst[64 * 256];   // 32KB, rows 512B, xor-swizzled
  __shared__ __align__(16) char qlds[4][2048];
  __shared__ __align__(16) char olds[4][2048];
  const int tid = threadIdx.x;
  const int w = tid >> 6, lane = tid & 63;
  const int c = lane & 15, g = lane >> 4;
  const int i0 = blockIdx.x * 512;
  const int bh = blockIdx.y;

  // stage K head-major (2048 chunks)
  #pragma unroll
  for (int q = 0; q < 8; ++q) {
    int cid = q * 256 + tid;
    int row = cid >> 3, cc = cid & 7;
    const bf16_t* src = Khi + (((size_t)bh * 256 + row) << 6) + ((cc ^ (row & 7)) << 3);
    async_ld16(src, (char*)kst + q * 4096 + w * 1024);
  }
  // stage V^T (2048 chunks)
  const char* vsrc0 = (const char*)(Vipt + (size_t)bh * 16384);
  #pragma unroll
  for (int q = 0; q < 8; ++q) {
    int L = (q * 256 + tid) * 16;
    int row = L >> 9;
    async_ld16(vsrc0 + (L ^ ((row & 7) << 4)), (char*)vst + q * 4096 + w * 1024);
  }
  // prologue Q(0), O(0)
  {
    int iq = i0 + w * 128;
    #pragma unroll
    for (int k2 = 0; k2 < 2; ++k2) {
      int k = k2 * 64 + lane, rr = k >> 3, cc = k & 7;
      size_t off = (((size_t)bh * 1024 + iq + rr) << 6) + ((cc ^ (rr & 7)) << 3);
      async_ld16(Qh + off, qlds[w] + k2 * 1024);
      async_ld16(Oh + off, olds[w] + k2 * 1024);
    }
  }
  __syncthreads();

  const float coef = tanhf(alpha[0]) + 1.0f;

  for (int st = 0; st < 8; ++st) {
    const int iq = i0 + w * 128 + st * 16;
    asm volatile("s_waitcnt vmcnt(0)" ::: "memory");
    bf16x8 qa0 = *(const bf16x8*)(qlds[w] + c * 128 + ((g ^ (c & 7)) << 4));
    bf16x8 qa1 = *(const bf16x8*)(qlds[w] + c * 128 + (((g + 4) ^ (c & 7)) << 4));
    asm volatile("s_waitcnt lgkmcnt(0)" ::: "memory");
    if (st < 7) {
      int iqn = iq + 16;
      #pragma unroll
      for (int k2 = 0; k2 < 2; ++k2) {
        int k = k2 * 64 + lane, rr = k >> 3, cc = k & 7;
        async_ld16(Qh + (((size_t)bh * 1024 + iqn + rr) << 6) + ((cc ^ (rr & 7)) << 3),
                   qlds[w] + k2 * 1024);
      }
    }
    f32x4 acc[4];
    #pragma unroll
    for (int dt = 0; dt < 4; ++dt) acc[dt] = (f32x4){0.f, 0.f, 0.f, 0.f};
    float m_run = -1e30f, l_run = 0.f;

    #pragma unroll
    for (int jt = 0; jt < 2; ++jt) {
      // S^T tile: mfma(K, Q) -> lane holds S^T[j=16n+4g+r][i=c]
      f32x4 s2[8];
      #pragma unroll
      for (int n = 0; n < 8; ++n) s2[n] = (f32x4){0.f, 0.f, 0.f, 0.f};
      const int sw = (c & 7) << 4;
      #pragma unroll
      for (int n = 0; n < 8; ++n) {
        int rb = (jt * 128 + n * 16 + c) * 128;
        bf16x8 k0 = *(const bf16x8*)((const char*)kst + rb + ((g << 4) ^ sw));
        bf16x8 k1 = *(const bf16x8*)((const char*)kst + rb + (((4 + g) << 4) ^ sw));
        s2[n] = MFMA16(k0, qa0, s2[n]);
        s2[n] = MFMA16(k1, qa1, s2[n]);
      }
      // online softmax over columns (i = c): stats lane-local + xor over g
      float mx = -1e30f;
      #pragma unroll
      for (int n = 0; n < 8; ++n)
        #pragma unroll
        for (int r = 0; r < 4; ++r) mx = fmaxf(mx, s2[n][r]);
      mx = fmaxf(mx, __shfl_xor(mx, 16));
      mx = fmaxf(mx, __shfl_xor(mx, 32));
      float m_new = fmaxf(m_run, mx);
      float fscale = exp2f((m_run - m_new) * SCALE_LOG2E);
      float tsum = 0.f;
      #pragma unroll
      for (int n = 0; n < 8; ++n)
        #pragma unroll
        for (int r = 0; r < 4; ++r) {
          float pv = exp2f((s2[n][r] - m_new) * SCALE_LOG2E);
          s2[n][r] = pv; tsum += pv;
        }
      tsum += __shfl_xor(tsum, 16);
      tsum += __shfl_xor(tsum, 32);
      l_run = l_run * fscale + tsum;
      m_run = m_new;
      #pragma unroll
      for (int dt = 0; dt < 4; ++dt) acc[dt] *= fscale;
      // PV: in-register P^T redistribution -> B-frag; A = V^T from LDS
      const int srcA = c | ((g & 1) << 5);
      const int srcB = srcA + 16;
      const bool hi_n = ((g >> 1) & 1) != 0;
      #pragma unroll
      for (int kt = 0; kt < 4; ++kt) {
        unsigned lo0 = pk2(s2[2 * kt][0], s2[2 * kt][1]);
        unsigned hi0 = pk2(s2[2 * kt][2], s2[2 * kt][3]);
        unsigned lo1 = pk2(s2[2 * kt + 1][0], s2[2 * kt + 1][1]);
        unsigned hi1 = pk2(s2[2 * kt + 1][2], s2[2 * kt + 1][3]);
        unsigned a0 = __shfl(lo0, srcA), a1 = __shfl(lo1, srcA);
        unsigned b0 = __shfl(hi0, srcA), b1 = __shfl(hi1, srcA);
        unsigned c0 = __shfl(lo0, srcB), c1 = __shfl(lo1, srcB);
        unsigned d0 = __shfl(hi0, srcB), d1 = __shfl(hi1, srcB);
        union { unsigned u[4]; bf16x8 v; } pf;
        pf.u[0] = hi_n ? a1 : a0;
        pf.u[1] = hi_n ? b1 : b0;
        pf.u[2] = hi_n ? c1 : c0;
        pf.u[3] = hi_n ? d1 : d0;
        #pragma unroll
        for (int dt = 0; dt < 4; ++dt) {
          int d = dt * 16 + c;
          int a = (d * 512 + jt * 256 + kt * 64 + g * 16) ^ ((c & 7) << 4);
          bf16x8 vf = *(const bf16x8*)((const char*)vst + a);
          acc[dt] = MFMA16(vf, pf.v, acc[dt]);
        }
      }
    }
    float inv = coef / l_run;
    asm volatile("s_waitcnt vmcnt(0)" ::: "memory");   // O(st) staged
    #pragma unroll
    for (int dt = 0; dt < 4; ++dt) {
      int chunk = dt * 2 + (g >> 1);
      char* pa = olds[w] + c * 128 + ((chunk ^ (c & 7)) << 4) + (g & 1) * 8;
      union { uint2 u2; bf16_t e[4]; } ov; ov.u2 = *(uint2*)pa;
      uint2 nv;
      nv.x = pk2((float)ov.e[0] + acc[dt][0] * inv, (float)ov.e[1] + acc[dt][1] * inv);
      nv.y = pk2((float)ov.e[2] + acc[dt][2] * inv, (float)ov.e[3] + acc[dt][3] * inv);
      *(uint2*)pa = nv;
    }
    char* ob = (char*)(Oh + (((size_t)bh * 1024 + iq) << 6));
    #pragma unroll
    for (int k2 = 0; k2 < 2; ++k2) {
      int k = k2 * 64 + lane, rr = k >> 3, cc = k & 7;
      uint4 v = *(uint4*)(olds[w] + rr * 128 + ((cc ^ (rr & 7)) << 4));
      *(uint4*)(ob + rr * 128 + cc * 16) = v;
    }
    asm volatile("s_waitcnt lgkmcnt(0)" ::: "memory"); // readout ds_reads retired
    if (st < 7) {
      int iqn = iq + 16;
      #pragma unroll
      for (int k2 = 0; k2 < 2; ++k2) {
        int k = k2 * 64 + lane, rr = k >> 3, cc = k & 7;
        async_ld16(Oh + (((size_t)bh * 1024 + iqn + rr) << 6) + ((cc ^ (rr & 7)) << 3),
                   olds[w] + k2 * 1024);
      }
    }
  }
}

// ---------------------------------------------------------------- launch
extern "C" void kernel_launch(void* const* d_in, const int* in_sizes, int n_in,
                              void* d_out, int out_size, void* d_ws, size_t ws_size,
                              hipStream_t stream)
{
  const float* x     = (const float*)d_in[0];
  const float* ctx   = (const float*)d_in[1];
  const float* W_q   = (const float*)d_in[2];
  const float* W_k   = (const float*)d_in[3];
  const float* W_v   = (const float*)d_in[4];
  const float* W_kip = (const float*)d_in[5];
  const float* W_vip = (const float*)d_in[6];
  const float* rel_k = (const float*)d_in[7];
  const float* rel_v = (const float*)d_in[8];
  const float* W_out = (const float*)d_in[9];
  const float* b_out = (const float*)d_in[10];
  const float* alpha = (const float*)d_in[11];

  char* ws = (char*)d_ws;
  bf16_t* Oh   = (bf16_t*)(ws + 0);            // [512][1024][64] (64MB)
  bf16_t* Qh   = (bf16_t*)(ws + 67108864);     // [512][1024][64] (64MB)
  bf16_t* CtxT = (bf16_t*)(ws + 134217728);    // [2560][1024] (5MB, 80 rows/b, 3 zero)
  bf16_t* CtxI = (bf16_t*)(ws + 139460608);    // [8192][1024] (16MB)
  bf16_t* WTs  = (bf16_t*)(ws + 156237824);    // 6 x 1024x1024 (12MB)
  bf16_t* WqT   = WTs + 0 * 1048576;
  bf16_t* WkT   = WTs + 1 * 1048576;   // WkT/WvT contiguous => N=2048 GEMM
  bf16_t* WkipT = WTs + 3 * 1048576;
  bf16_t* WoutT = WTs + 5 * 1048576;

  char* dob = (char*)d_out;
  bf16_t* Khi   = (bf16_t*)(dob + 0);           // [512][256][64] (16MB)
  bf16_t* Vhi   = (bf16_t*)(dob + 16777216);    // [512][256][64] (16MB)
  bf16_t* Vipt  = (bf16_t*)(dob + 33554432);    // [512][64][256] (16MB)
  bf16_t* Kth   = (bf16_t*)(dob + 50331648);    // [512][80][64] (5MB)
  bf16_t* Vth   = (bf16_t*)(dob + 55574528);    // [512][80][64] (5MB)
  bf16_t* Vtt   = (bf16_t*)(dob + 60817408);    // [512][64][80] (5MB)
  bf16_t* Rkb   = (bf16_t*)(dob + 66060288);    // [2048][64] (256KB)
  bf16_t* RvT   = (bf16_t*)(dob + 66322432);    // [64][2048] (256KB)
  bf16_t* Xb    = (bf16_t*)(dob + 66584576);    // [32768][1024] bf16 (64MB), dead before out-GEMM

  // converts / transposes
  k_cvt_x<<<16384, 256, 0, stream>>>(x, Xb);
  k_cvt_ctx<<<BATCH * CTXLEN, 128, 0, stream>>>(ctx, CtxT, CtxI);
  k_transpose_w6<<<dim3(32, 32, 6), dim3(32, 8), 0, stream>>>(W_q, W_k, W_v, W_kip, W_vip, W_out, WTs);
  k_cvt_relk<<<64, 256, 0, stream>>>(rel_k, Rkb);
  k_cvt_relvT<<<64, 256, 0, stream>>>(rel_v, RvT);

  // projections (head-major outputs); BM=256 x BN=128, 512 threads
  k_gemm<4, false><<<dim3(128, 8),  512, 0, stream>>>(Xb,   WqT,   (void*)Qh,  nullptr,     nullptr, 32768, 1024, 1024);
  k_gemm<5, false><<<dim3(10, 16),  512, 0, stream>>>(CtxT, WkT,   (void*)Kth, (void*)Vth,  nullptr, 2560,  2048, 1024);
  k_gemm<6, false><<<dim3(32, 16),  512, 0, stream>>>(CtxI, WkipT, (void*)Khi, (void*)Vhi,  nullptr, 8192,  2048, 1024);

  // V transposes (head-major input)
  k_vtrans<80,  80 ><<<2 * 512, 256, 0, stream>>>(Vth, Vtt);
  k_vtrans<256, 256><<<4 * 512, 256, 0, stream>>>(Vhi, Vipt);

  // attention: txt writes Oh, img RMW-adds
  k_txt<<<512, 256, 0, stream>>>(Qh, Kth, Vtt, Rkb, RvT, Oh);
  k_img<<<dim3(2, 512), 256, 0, stream>>>(Qh, Khi, Vipt, alpha, Oh);

  // output projection + bias (head-major A)
  k_gemm<2, true><<<dim3(128, 8), 512, 0, stream>>>(Oh, WoutT, d_out, nullptr, b_out, 32768, 1024, 1024);
}